// Round 2
// baseline (1817.228 us; speedup 1.0000x reference)
//
#include <hip/hip_runtime.h>
#include <math.h>

#define DIMC 64
#define C2 340
#define HID 170
#define IMG 256
#define HW 65536          // 256*256
#define NQ 85             // 340/4 channel quads

// ws float offsets (weights area), z chunk buffer follows
#define OFF_K   0          // Kc4: [64 d][85 q] float4 -> 21760 floats
#define OFF_WT  21760      // WT4: [64 in][85 q] float4 -> 21760 floats
#define OFF_WOT 43520      // WoutT: [170][64] -> 10880 floats
#define OFF_Z   54400      // z chunk: [340][nrh*8][256] floats (adaptive)

// ---------------------------------------------------------------------------
// Precompute the equivalent circular-conv kernel from the rFFT filter:
// K_c[d1][d2] = (1/64) sum_{k1=0..7} sum_{k2=0..4} a(k2)*F[c][k1][k2]*cos(2pi(k1 d1 + k2 d2)/8)
// a = 1 for k2 in {0,4}, else 2 (c2r ignores imag of DC/Nyquist bins).
// Verified analytically: equals rfft2 -> *F (real) -> irfft2 per patch.
// Stored as Kc4[d][q].j = K[4q+j][d] for uniform vector loads in stage 2.
// ---------------------------------------------------------------------------
__global__ void k_prep_k(const float* __restrict__ f, float* __restrict__ ws) {
    __shared__ float ct[8];
    int c = blockIdx.x;      // 0..339
    int d = threadIdx.x;     // 0..63
    if (d < 8) {
        const float S = 0.70710678118654752440f;
        float v;
        switch (d) {
            case 0: v = 1.f; break;
            case 1: v = S; break;
            case 2: v = 0.f; break;
            case 3: v = -S; break;
            case 4: v = -1.f; break;
            case 5: v = -S; break;
            case 6: v = 0.f; break;
            default: v = S; break;
        }
        ct[d] = v;
    }
    __syncthreads();
    int d1 = d >> 3, d2 = d & 7;
    float acc = 0.f;
    #pragma unroll
    for (int k1 = 0; k1 < 8; ++k1) {
        #pragma unroll
        for (int k2 = 0; k2 < 5; ++k2) {
            float a = (k2 == 0 || k2 == 4) ? 1.f : 2.f;
            acc += a * f[c * 40 + k1 * 5 + k2] * ct[(k1 * d1 + k2 * d2) & 7];
        }
    }
    acc *= (1.f / 64.f);
    ws[OFF_K + (size_t)(d * NQ + (c >> 2)) * 4 + (c & 3)] = acc;
}

// Transpose W_in into WT4[in][q].j = W_in[4q+j][in]; WoutT[c][o] = W_out[o][c].
__global__ void k_prep_w(const float* __restrict__ Win, const float* __restrict__ Wout,
                         float* __restrict__ ws) {
    int t = blockIdx.x * 256 + threadIdx.x;
    if (t < 64 * C2) {
        int in = t / C2, c = t % C2;
        ws[OFF_WT + (size_t)(in * NQ + (c >> 2)) * 4 + (c & 3)] = Win[c * DIMC + in];
    }
    if (t < HID * 64) {
        int c = t >> 6, o = t & 63;
        ws[OFF_WOT + t] = Wout[o * HID + c];
    }
}

// ---------------------------------------------------------------------------
// Fused project_in (64->340 1x1 conv) + per-channel 8x8 circular conv.
// Processes patch rows [pr0, pr0+nr) of batch b; z chunk layout [c][yloc][x]
// with yloc = y - pr0*8, channel stride nr*2048.
// One block per patch. 4 waves; each wave owns a 4-channel quad per iter.
// Stage 1: lane = pixel m, 4 accumulators, wave-uniform float4 weights.
// Stage 2: doubled 16x16 LDS buffer makes the circular shift a constant
// immediate offset per tap.
// ---------------------------------------------------------------------------
__global__ __launch_bounds__(256) void k_proj_conv(const float* __restrict__ x,
                                                   const float* __restrict__ ws,
                                                   float* __restrict__ z,
                                                   int b, int pr0, int nr) {
    __shared__ float xs[64 * 64];        // [in][m] patch pixels, 16 KB
    __shared__ float4 pbuf[4][256];      // per-wave doubled prj buffer, 16 KB

    int blk = blockIdx.x;
    int pyl = blk >> 5;                  // 0..nr-1 (local patch row)
    int px = blk & 31;
    int py = pr0 + pyl;                  // global patch row
    int tid = threadIdx.x;
    size_t CS = (size_t)nr * 2048;       // channel stride in z chunk

    const float* xb = x + (size_t)b * DIMC * HW + (size_t)(py * 8) * IMG + px * 8;
    for (int u = tid; u < 512; u += 256) {
        int in = u >> 3, r = u & 7;
        const float* src = xb + (size_t)in * HW + r * IMG;
        float4 a = *(const float4*)src;
        float4 c = *(const float4*)(src + 4);
        *(float4*)&xs[in * 64 + r * 8] = a;
        *(float4*)&xs[in * 64 + r * 8 + 4] = c;
    }
    __syncthreads();

    int w = tid >> 6, lane = tid & 63;
    int n1 = lane >> 3, n2 = lane & 7;
    int lanebase = n1 * 16 + n2;
    const float4* WT4 = (const float4*)(ws + OFF_WT);
    const float4* KC4 = (const float4*)(ws + OFF_K);

    for (int it = 0; it < 22; ++it) {
        int q = __builtin_amdgcn_readfirstlane(w + it * 4);
        bool act = (q < NQ);
        if (act) {
            // stage 1: prj[4ch] for pixel m = lane
            float4 pv = make_float4(0.f, 0.f, 0.f, 0.f);
            #pragma unroll
            for (int in = 0; in < 64; ++in) {
                float xv = xs[in * 64 + lane];
                float4 wv = WT4[in * NQ + q];
                pv.x += wv.x * xv; pv.y += wv.y * xv;
                pv.z += wv.z * xv; pv.w += wv.w * xv;
            }
            // doubled write: pbuf[r][c] = prj[r&7][c&7]
            pbuf[w][lanebase] = pv;
            pbuf[w][lanebase + 8] = pv;
            pbuf[w][lanebase + 128] = pv;
            pbuf[w][lanebase + 136] = pv;
        }
        __syncthreads();
        if (act) {
            // stage 2: z[n] = sum_d K[d]*prj[(n-d) mod (8,8)]
            float4 zv = make_float4(0.f, 0.f, 0.f, 0.f);
            #pragma unroll
            for (int d1 = 0; d1 < 8; ++d1) {
                #pragma unroll
                for (int d2 = 0; d2 < 8; ++d2) {
                    float4 kv = KC4[(d1 * 8 + d2) * NQ + q];
                    float4 pr = pbuf[w][lanebase + (8 - d1) * 16 + (8 - d2)];
                    zv.x += kv.x * pr.x; zv.y += kv.y * pr.y;
                    zv.z += kv.z * pr.z; zv.w += kv.w * pr.w;
                }
            }
            float* zc = z + (size_t)(q * 4) * CS
                      + (size_t)(pyl * 8 + n1) * IMG + px * 8 + n2;
            zc[0] = zv.x;
            zc[CS] = zv.y;
            zc[2 * CS] = zv.z;
            zc[3 * CS] = zv.w;
        }
        __syncthreads();
    }
}

// ---------------------------------------------------------------------------
// Fused depthwise 3x3 (zero pad) + exact GELU-GLU + project_out GEMM.
// Consumes tile rows [tr0, tr0+ntr) of batch b from a z chunk that covers
// patch rows [pr0h, pr0h+nrh) (halo rows included).
// ---------------------------------------------------------------------------
__device__ __forceinline__ float gelu_exact(float v) {
    return 0.5f * v * (1.f + erff(v * 0.70710678118654752440f));
}

__global__ __launch_bounds__(256) void k_post(const float* __restrict__ z,
                                              const float* __restrict__ wdw,
                                              const float* __restrict__ ws,
                                              float* __restrict__ out,
                                              int b, int tr0, int pr0h, int nrh) {
    __shared__ float gbuf[HID * 64];     // 43.5 KB
    int blk = blockIdx.x;
    int ty = tr0 + (blk >> 5), tx = blk & 31;
    int tid = threadIdx.x;
    int gy0 = ty * 8, gx0 = tx * 8;
    size_t CS = (size_t)nrh * 2048;
    int ybase = pr0h * 8;

    for (int u = tid; u < HID * 64; u += 256) {
        int c = u >> 6, pix = u & 63;
        int yy = gy0 + (pix >> 3), xx = gx0 + (pix & 7);
        const float* z1 = z + (size_t)c * CS;
        const float* z2 = z1 + (size_t)HID * CS;
        const float* wd1 = wdw + c * 9;
        const float* wd2 = wdw + (c + HID) * 9;
        float d1 = 0.f, d2 = 0.f;
        #pragma unroll
        for (int dy = -1; dy <= 1; ++dy) {
            int y = yy + dy;
            bool yok = ((unsigned)y < (unsigned)IMG);
            #pragma unroll
            for (int dx = -1; dx <= 1; ++dx) {
                int xq = xx + dx;
                bool ok = yok && ((unsigned)xq < (unsigned)IMG);
                float v1 = 0.f, v2 = 0.f;
                if (ok) {
                    size_t off = (size_t)(y - ybase) * IMG + xq;
                    v1 = z1[off];
                    v2 = z2[off];
                }
                float w1 = wd1[(dy + 1) * 3 + (dx + 1)];
                float w2 = wd2[(dy + 1) * 3 + (dx + 1)];
                d1 += w1 * v1;
                d2 += w2 * v2;
            }
        }
        gbuf[u] = gelu_exact(d1) * d2;
    }
    __syncthreads();

    int w = tid >> 6, lane = tid & 63;
    int ob = w * 16;
    float acc[16];
    #pragma unroll
    for (int k = 0; k < 16; ++k) acc[k] = 0.f;
    const float* WoT = ws + OFF_WOT;
    for (int c = 0; c < HID; ++c) {
        float gv = gbuf[c * 64 + lane];
        const float* wp = WoT + c * 64 + ob;
        #pragma unroll
        for (int k = 0; k < 16; ++k) acc[k] += wp[k] * gv;
    }
    int yy = gy0 + (lane >> 3), xx = gx0 + (lane & 7);
    #pragma unroll
    for (int k = 0; k < 16; ++k)
        out[((size_t)b * 64 + ob + k) * HW + (size_t)yy * IMG + xx] = acc[k];
}

// ---------------------------------------------------------------------------
extern "C" void kernel_launch(void* const* d_in, const int* in_sizes, int n_in,
                              void* d_out, int out_size, void* d_ws, size_t ws_size,
                              hipStream_t stream) {
    const float* x    = (const float*)d_in[0];
    const float* Win  = (const float*)d_in[1];
    const float* Wdw  = (const float*)d_in[2];
    const float* ff   = (const float*)d_in[3];
    const float* Wout = (const float*)d_in[4];
    float* out = (float*)d_out;
    float* ws  = (float*)d_ws;
    float* zbuf = ws + OFF_Z;

    hipLaunchKernelGGL(k_prep_k, dim3(C2), dim3(64), 0, stream, ff, ws);
    hipLaunchKernelGGL(k_prep_w, dim3(85), dim3(256), 0, stream, Win, Wout, ws);

    // Adaptive z-chunking: a chunk of R patch rows needs (R+2 halo, capped 32)
    // patch rows of z = 340*2048*h floats. Pick the largest R that fits d_ws.
    size_t capf = ws_size / sizeof(float);
    capf = (capf > OFF_Z) ? capf - OFF_Z : 0;
    const size_t perRow = (size_t)C2 * 2048;   // floats per patch-row of z
    int R;
    if (capf >= perRow * 32) {
        R = 32;                                 // full image per batch, no halo recompute
    } else {
        long t = (long)(capf / perRow) - 2;
        R = (t < 1) ? 1 : (t > 32 ? 32 : (int)t);
    }

    for (int b = 0; b < 4; ++b) {
        for (int pr = 0; pr < 32; pr += R) {
            int tr1 = (pr + R < 32) ? pr + R : 32;
            int pr0h = (pr > 0) ? pr - 1 : 0;
            int pr1h = (tr1 < 32) ? tr1 + 1 : 32;
            int nrh = pr1h - pr0h;
            int ntr = tr1 - pr;
            hipLaunchKernelGGL(k_proj_conv, dim3(nrh * 32), dim3(256), 0, stream,
                               x, ws, zbuf, b, pr0h, nrh);
            hipLaunchKernelGGL(k_post, dim3(ntr * 32), dim3(256), 0, stream,
                               zbuf, Wdw, ws, out, b, pr, pr0h, nrh);
        }
    }
}

// Round 3
// 1563.405 us; speedup vs baseline: 1.1624x; 1.1624x over previous
//
#include <hip/hip_runtime.h>
#include <math.h>

#define DIMC 64
#define C2 340
#define HID 170
#define IMG 256
#define HW 65536          // 256*256
#define NQ 85             // 340/4 channel quads

// ws float offsets (weights area), z chunk buffer follows
#define OFF_WTQ 0          // WT4q[85 q][64 in] float4 (.j = W_in[4q+j][in])        21760 f
#define OFF_KCQ 21760      // KC4q[85 q][64 d]  float4 (.j = K[4q+j][d])            21760 f
#define OFF_WDI 43520      // wdwI[9 t][340 ic] interleaved depthwise weights        3060 f
#define OFF_WOT 46580      // WoutT[170 c][64 o]                                    10880 f
#define OFF_Z   57460      // z chunk: [nrh*8*256 pix][340 ic] floats (adaptive)

// interleaved channel position: orig o<170 -> 2o ; o>=170 -> 2(o-170)+1
__device__ __forceinline__ int ipos(int o) { return (o < HID) ? (o << 1) : (((o - HID) << 1) + 1); }

// ---------------------------------------------------------------------------
// K_c[d1][d2] = (1/64) sum_{k1<8,k2<5} a(k2)*F[c][k1][k2]*cos(2pi(k1 d1+k2 d2)/8),
// a=1 for k2 in {0,4} else 2.  (rfft2 -> *realF -> irfft2 == circular conv by K.)
// ---------------------------------------------------------------------------
__global__ void k_prep_k(const float* __restrict__ f, float* __restrict__ ws) {
    __shared__ float ct[8];
    int c = blockIdx.x;      // 0..339
    int d = threadIdx.x;     // 0..63
    if (d < 8) {
        const float S = 0.70710678118654752440f;
        float v;
        switch (d) {
            case 0: v = 1.f; break;
            case 1: v = S; break;
            case 2: v = 0.f; break;
            case 3: v = -S; break;
            case 4: v = -1.f; break;
            case 5: v = -S; break;
            case 6: v = 0.f; break;
            default: v = S; break;
        }
        ct[d] = v;
    }
    __syncthreads();
    int d1 = d >> 3, d2 = d & 7;
    float acc = 0.f;
    #pragma unroll
    for (int k1 = 0; k1 < 8; ++k1) {
        #pragma unroll
        for (int k2 = 0; k2 < 5; ++k2) {
            float a = (k2 == 0 || k2 == 4) ? 1.f : 2.f;
            acc += a * f[c * 40 + k1 * 5 + k2] * ct[(k1 * d1 + k2 * d2) & 7];
        }
    }
    ws[OFF_KCQ + (size_t)((c >> 2) * 64 + d) * 4 + (c & 3)] = acc * (1.f / 64.f);
}

__global__ void k_prep_w(const float* __restrict__ Win, const float* __restrict__ Wdw,
                         const float* __restrict__ Wout, float* __restrict__ ws) {
    int t = blockIdx.x * 256 + threadIdx.x;
    if (t < C2 * 64) {               // WT4q
        int c = t >> 6, in = t & 63;
        ws[OFF_WTQ + (size_t)((c >> 2) * 64 + in) * 4 + (c & 3)] = Win[c * DIMC + in];
    }
    if (t < 9 * C2) {                // wdwI (interleaved depthwise weights)
        int tt = t / C2, ic = t % C2;
        int o = (ic & 1) ? ((ic >> 1) + HID) : (ic >> 1);
        ws[OFF_WDI + tt * C2 + ic] = Wdw[o * 9 + tt];
    }
    if (t < HID * 64) {              // WoutT
        int c = t >> 6, o = t & 63;
        ws[OFF_WOT + t] = Wout[o * HID + c];
    }
}

// ---------------------------------------------------------------------------
// Fused project_in + per-channel 8x8 circular conv.  One block per patch.
// Per iteration each wave owns one 4-channel quad; weights for the quad are
// double-buffer staged into LDS (kills the per-iter s_load storm of R2).
// Output z is pixel-major, GLU-interleaved: z[pix][ipos(o)].
// ---------------------------------------------------------------------------
__global__ __launch_bounds__(256) void k_proj_conv(const float* __restrict__ x,
                                                   const float* __restrict__ ws,
                                                   float* __restrict__ z,
                                                   int b, int pr0, int nr) {
    __shared__ float xs[64 * 64];           // [in][pix] 16 KB
    __shared__ float4 pbuf[4][272];         // padded 16x17 doubled prj buffer, 17.4 KB
    __shared__ float4 wstage[2][4][128];    // dbuf x wave x (64 WT | 64 KC), 16 KB

    int blk = blockIdx.x;
    int pyl = blk >> 5, px = blk & 31;
    int py = pr0 + pyl;
    int tid = threadIdx.x;
    int w = tid >> 6, lane = tid & 63;
    int n1 = lane >> 3, n2 = lane & 7;
    int lanebase = n1 * 17 + n2;

    const float4* WT4 = (const float4*)(ws + OFF_WTQ);
    const float4* KC4 = (const float4*)(ws + OFF_KCQ);

    // load x patch  [in][8x8]
    const float* xb = x + (size_t)b * DIMC * HW + (size_t)(py * 8) * IMG + px * 8;
    for (int u = tid; u < 512; u += 256) {
        int in = u >> 3, r = u & 7;
        const float* src = xb + (size_t)in * HW + r * IMG;
        *(float4*)&xs[in * 64 + r * 8]     = *(const float4*)src;
        *(float4*)&xs[in * 64 + r * 8 + 4] = *(const float4*)(src + 4);
    }
    // prologue: stage quads q=w into wstage[0]
    wstage[0][w][lane]      = WT4[w * 64 + lane];
    wstage[0][w][64 + lane] = KC4[w * 64 + lane];
    __syncthreads();

    for (int it = 0; it < 22; ++it) {
        int cur = it & 1, nxt = cur ^ 1;
        int q = w + it * 4;
        int qn = q + 4;
        bool act = (q < NQ);
        bool nact = (qn < NQ);
        float4 nw0, nw1;
        if (nact) {                          // issue next-iter weight loads early
            nw0 = WT4[qn * 64 + lane];
            nw1 = KC4[qn * 64 + lane];
        }
        if (act) {
            // stage 1: prj[4ch] for pixel m = lane (weights from LDS, broadcast)
            float4 pv = make_float4(0.f, 0.f, 0.f, 0.f);
            #pragma unroll
            for (int in = 0; in < 64; ++in) {
                float xv = xs[in * 64 + lane];
                float4 wv = wstage[cur][w][in];
                pv.x += wv.x * xv; pv.y += wv.y * xv;
                pv.z += wv.z * xv; pv.w += wv.w * xv;
            }
            pbuf[w][lanebase]             = pv;
            pbuf[w][lanebase + 8]         = pv;
            pbuf[w][lanebase + 8 * 17]    = pv;
            pbuf[w][lanebase + 8 * 17 + 8]= pv;
        }
        if (nact) {
            wstage[nxt][w][lane]      = nw0;
            wstage[nxt][w][64 + lane] = nw1;
        }
        __syncthreads();                     // pbuf ready; next weights staged
        if (act) {
            float4 zv = make_float4(0.f, 0.f, 0.f, 0.f);
            #pragma unroll
            for (int d1 = 0; d1 < 8; ++d1) {
                #pragma unroll
                for (int d2 = 0; d2 < 8; ++d2) {
                    float4 kv = wstage[cur][w][64 + d1 * 8 + d2];
                    float4 pr = pbuf[w][(n1 + 8 - d1) * 17 + (n2 + 8 - d2)];
                    zv.x += kv.x * pr.x; zv.y += kv.y * pr.y;
                    zv.z += kv.z * pr.z; zv.w += kv.w * pr.w;
                }
            }
            // pixel-major, GLU-interleaved scatter store (4 scalars; L2 merges)
            size_t pix = (size_t)(pyl * 8 + n1) * IMG + px * 8 + n2;
            float* zp = z + pix * C2;
            int o = q * 4;
            zp[ipos(o)]     = zv.x;
            zp[ipos(o + 1)] = zv.y;
            zp[ipos(o + 2)] = zv.z;
            zp[ipos(o + 3)] = zv.w;
        }
        __syncthreads();                     // pbuf free
    }
}

// ---------------------------------------------------------------------------
// Fused depthwise 3x3 (zero pad) + exact GELU-GLU + project_out GEMM.
// Phase A: lane = pixel, wave-uniform channel-group cg (covers GLU ch 2cg,2cg+1).
// One float4 load per tap gives both halves of two GLU channels. Weights via
// wave-uniform s_loads. Phase B: 16 out-ch register blocking per wave.
// ---------------------------------------------------------------------------
__device__ __forceinline__ float gelu_exact(float v) {
    return 0.5f * v * (1.f + erff(v * 0.70710678118654752440f));
}

__global__ __launch_bounds__(256) void k_post(const float* __restrict__ z,
                                              const float* __restrict__ ws,
                                              float* __restrict__ out,
                                              int b, int tr0, int pr0h, int nrh) {
    __shared__ float gbuf[HID * 64];     // 43.5 KB
    int blk = blockIdx.x;
    int ty = tr0 + (blk >> 5), tx = blk & 31;
    int tid = threadIdx.x;
    int w = tid >> 6, lane = tid & 63;
    int gy0 = ty * 8, gx0 = tx * 8;
    int ybase = pr0h * 8;

    int yy = gy0 + (lane >> 3), xx = gx0 + (lane & 7);
    const float* zpix = z + ((size_t)(yy - ybase) * IMG + xx) * C2;

    for (int cg = w; cg < NQ; cg += 4) {
        int scg = __builtin_amdgcn_readfirstlane(cg);
        float4 a = make_float4(0.f, 0.f, 0.f, 0.f);
        #pragma unroll
        for (int t = 0; t < 9; ++t) {
            const int dy = t / 3 - 1, dx = t % 3 - 1;
            float4 wv = *(const float4*)(ws + OFF_WDI + t * C2 + 4 * scg);
            bool ok = ((unsigned)(yy + dy) < (unsigned)IMG) &&
                      ((unsigned)(xx + dx) < (unsigned)IMG);
            if (ok) {
                float4 v = *(const float4*)(zpix + (dy * IMG + dx) * C2 + 4 * scg);
                a.x += wv.x * v.x; a.y += wv.y * v.y;
                a.z += wv.z * v.z; a.w += wv.w * v.w;
            }
        }
        // a = (dw1[2cg], dw2[2cg], dw1[2cg+1], dw2[2cg+1])
        gbuf[(2 * scg) * 64 + lane]     = gelu_exact(a.x) * a.y;
        gbuf[(2 * scg + 1) * 64 + lane] = gelu_exact(a.z) * a.w;
    }
    __syncthreads();

    int ob = __builtin_amdgcn_readfirstlane((tid >> 6) * 16);
    float acc[16];
    #pragma unroll
    for (int k = 0; k < 16; ++k) acc[k] = 0.f;
    const float* WoT = ws + OFF_WOT;
    for (int c = 0; c < HID; ++c) {
        float gv = gbuf[c * 64 + lane];
        const float* wp = WoT + c * 64 + ob;
        #pragma unroll
        for (int k = 0; k < 16; ++k) acc[k] += wp[k] * gv;
    }
    #pragma unroll
    for (int k = 0; k < 16; ++k)
        out[((size_t)b * 64 + ob + k) * HW + (size_t)yy * IMG + xx] = acc[k];
}

// ---------------------------------------------------------------------------
extern "C" void kernel_launch(void* const* d_in, const int* in_sizes, int n_in,
                              void* d_out, int out_size, void* d_ws, size_t ws_size,
                              hipStream_t stream) {
    const float* x    = (const float*)d_in[0];
    const float* Win  = (const float*)d_in[1];
    const float* Wdw  = (const float*)d_in[2];
    const float* ff   = (const float*)d_in[3];
    const float* Wout = (const float*)d_in[4];
    float* out = (float*)d_out;
    float* ws  = (float*)d_ws;
    float* zbuf = ws + OFF_Z;

    hipLaunchKernelGGL(k_prep_k, dim3(C2), dim3(64), 0, stream, ff, ws);
    hipLaunchKernelGGL(k_prep_w, dim3(85), dim3(256), 0, stream, Win, Wdw, Wout, ws);

    // Adaptive z-chunking: chunk of R patch rows needs (R+2, capped 32) rows.
    size_t capf = ws_size / sizeof(float);
    capf = (capf > OFF_Z) ? capf - OFF_Z : 0;
    const size_t perRow = (size_t)C2 * 2048;
    int R;
    if (capf >= perRow * 32) {
        R = 32;
    } else {
        long t = (long)(capf / perRow) - 2;
        R = (t < 1) ? 1 : (t > 32 ? 32 : (int)t);
    }

    for (int b = 0; b < 4; ++b) {
        for (int pr = 0; pr < 32; pr += R) {
            int tr1 = (pr + R < 32) ? pr + R : 32;
            int pr0h = (pr > 0) ? pr - 1 : 0;
            int pr1h = (tr1 < 32) ? tr1 + 1 : 32;
            int nrh = pr1h - pr0h;
            int ntr = tr1 - pr;
            hipLaunchKernelGGL(k_proj_conv, dim3(nrh * 32), dim3(256), 0, stream,
                               x, ws, zbuf, b, pr0h, nrh);
            hipLaunchKernelGGL(k_post, dim3(ntr * 32), dim3(256), 0, stream,
                               zbuf, ws, out, b, pr, pr0h, nrh);
        }
    }
}